// Round 1
// baseline (5305.799 us; speedup 1.0000x reference)
//
#include <hip/hip_runtime.h>

#define N_NODES 100000
#define N_TYPES 7
#define N_EDGES 400000
#define DIM 128

// ---------------------------------------------------------------------------
// Phase 1: per-type scatter. Each edge handled by 32 lanes (4 floats each).
// Gather x[src] (float4, coalesced 512B/edge) and atomicAdd into summed[dst].
// Lane 0 also bumps the edge count for dst.
// ---------------------------------------------------------------------------
__global__ __launch_bounds__(256) void scatter_kernel(
    const float* __restrict__ x,
    const int* __restrict__ src,
    const int* __restrict__ dst,
    float* __restrict__ summed,
    float* __restrict__ cnt)
{
    int tid = blockIdx.x * 256 + threadIdx.x;
    int e = tid >> 5;
    if (e >= N_EDGES) return;
    int l = tid & 31;
    int s = src[e];
    int d = dst[e];
    float4 v = *reinterpret_cast<const float4*>(x + (size_t)s * DIM + l * 4);
    float* o = summed + (size_t)d * DIM + l * 4;
    atomicAdd(o + 0, v.x);
    atomicAdd(o + 1, v.y);
    atomicAdd(o + 2, v.z);
    atomicAdd(o + 3, v.w);
    if (l == 0) atomicAdd(cnt + d, 1.0f);
}

// ---------------------------------------------------------------------------
// Phase 2: out += ((summed / max(cnt,1)) @ W + b) * (1/7)
// Block: 256 threads -> 32 rows x 128 cols tile. Thread: 4x4 register tile.
// K tiled by 32; W k-tile (16 KB) + mean tile (with /cnt fused) in LDS.
// float4 LDS reads keep the LDS pipe ~balanced with VALU.
// ---------------------------------------------------------------------------
#define BR 32
__global__ __launch_bounds__(256) void matmul_kernel(
    const float* __restrict__ summed,
    const float* __restrict__ cnt,
    const float* __restrict__ W,      // [DIM][DIM], row k, col j
    const float* __restrict__ bias,   // [DIM]
    float* __restrict__ out)
{
    __shared__ float sW[32][DIM];     // 16 KB
    __shared__ float sM[BR][36];      // stride 36 keeps 16B alignment, 4.6 KB

    const int row0 = blockIdx.x * BR;
    const int cg = threadIdx.x & 31;  // col group: cols 4*cg .. 4*cg+3
    const int rg = threadIdx.x >> 5;  // row group: rows rg*4 .. rg*4+3

    float acc[4][4];
#pragma unroll
    for (int r = 0; r < 4; ++r)
#pragma unroll
        for (int c = 0; c < 4; ++c) acc[r][c] = 0.f;

    for (int k0 = 0; k0 < DIM; k0 += 32) {
        // stage W[k0:k0+32][0:128] : 1024 float4, 4 per thread
#pragma unroll
        for (int i = 0; i < 4; ++i) {
            int idx4 = threadIdx.x + i * 256;        // 0..1023
            int kk = idx4 >> 5;
            int jc = idx4 & 31;
            *reinterpret_cast<float4*>(&sW[kk][jc * 4]) =
                *reinterpret_cast<const float4*>(&W[(size_t)(k0 + kk) * DIM + jc * 4]);
        }
        // stage mean rows: 32 rows x 32 k's, 1 float4 per thread, /cnt fused
        {
            int r = threadIdx.x >> 3;                // 0..31
            int kkc = threadIdx.x & 7;               // 0..7 (float4 groups)
            int row = row0 + r;
            float4 v = make_float4(0.f, 0.f, 0.f, 0.f);
            if (row < N_NODES) {
                float inv = 1.0f / fmaxf(cnt[row], 1.0f);
                float4 s = *reinterpret_cast<const float4*>(
                    &summed[(size_t)row * DIM + k0 + kkc * 4]);
                v.x = s.x * inv; v.y = s.y * inv; v.z = s.z * inv; v.w = s.w * inv;
            }
            *reinterpret_cast<float4*>(&sM[r][kkc * 4]) = v;
        }
        __syncthreads();

#pragma unroll
        for (int kk = 0; kk < 32; kk += 4) {
            float wv[4][4];
#pragma unroll
            for (int q = 0; q < 4; ++q) {
                float4 t = *reinterpret_cast<const float4*>(&sW[kk + q][cg * 4]);
                wv[q][0] = t.x; wv[q][1] = t.y; wv[q][2] = t.z; wv[q][3] = t.w;
            }
#pragma unroll
            for (int r = 0; r < 4; ++r) {
                float4 t = *reinterpret_cast<const float4*>(&sM[rg * 4 + r][kk]);
                float m[4] = {t.x, t.y, t.z, t.w};
#pragma unroll
                for (int q = 0; q < 4; ++q)
#pragma unroll
                    for (int c = 0; c < 4; ++c)
                        acc[r][c] += m[q] * wv[q][c];
            }
        }
        __syncthreads();
    }

    const float inv7 = 1.0f / 7.0f;
    float bj[4];
#pragma unroll
    for (int c = 0; c < 4; ++c) bj[c] = bias[cg * 4 + c];

#pragma unroll
    for (int r = 0; r < 4; ++r) {
        int row = row0 + rg * 4 + r;
        if (row < N_NODES) {
            float4* po = reinterpret_cast<float4*>(&out[(size_t)row * DIM + cg * 4]);
            float4 cur = *po;
            cur.x += (acc[r][0] + bj[0]) * inv7;
            cur.y += (acc[r][1] + bj[1]) * inv7;
            cur.z += (acc[r][2] + bj[2]) * inv7;
            cur.w += (acc[r][3] + bj[3]) * inv7;
            *po = cur;
        }
    }
}

extern "C" void kernel_launch(void* const* d_in, const int* in_sizes, int n_in,
                              void* d_out, int out_size, void* d_ws, size_t ws_size,
                              hipStream_t stream) {
    const float* x  = (const float*)d_in[0];
    const int*   ei = (const int*)d_in[1];     // [N_TYPES, 2, N_EDGES] int32
    const float* W  = (const float*)d_in[2];   // [N_TYPES, DIM, DIM]
    const float* b  = (const float*)d_in[3];   // [N_TYPES, DIM]
    float* out = (float*)d_out;

    float* summed = (float*)d_ws;                       // N_NODES*DIM floats
    float* cnt = summed + (size_t)N_NODES * DIM;        // N_NODES floats
    const size_t ws_bytes = ((size_t)N_NODES * DIM + N_NODES) * sizeof(float);

    hipMemsetAsync(out, 0, (size_t)N_NODES * DIM * sizeof(float), stream);

    const int scatter_blocks = (N_EDGES * 32 + 255) / 256;   // 50000
    const int matmul_blocks = (N_NODES + BR - 1) / BR;       // 3125

    for (int t = 0; t < N_TYPES; ++t) {
        const int* src = ei + (size_t)t * 2 * N_EDGES;
        const int* dst = src + N_EDGES;
        hipMemsetAsync(summed, 0, ws_bytes, stream);
        scatter_kernel<<<scatter_blocks, 256, 0, stream>>>(x, src, dst, summed, cnt);
        matmul_kernel<<<matmul_blocks, 256, 0, stream>>>(
            summed, cnt, W + (size_t)t * DIM * DIM, b + (size_t)t * DIM, out);
    }
}

// Round 2
// 938.093 us; speedup vs baseline: 5.6559x; 5.6559x over previous
//
#include <hip/hip_runtime.h>

#define N_NODES 100000
#define N_TYPES 7
#define N_EDGES 400000
#define DIM 128
#define NTOT (N_TYPES * N_NODES)   // 700000 segments
#define ETOT (N_TYPES * N_EDGES)   // 2800000 edges total

// ---------------------------------------------------------------------------
// CSR build: histogram -> exclusive scan (2-level) -> fill (counting sort)
// ---------------------------------------------------------------------------
__global__ __launch_bounds__(256) void hist_kernel(
    const int* __restrict__ ei, int* __restrict__ deg)
{
    int i = blockIdx.x * 256 + threadIdx.x;
    if (i >= ETOT) return;
    int t = i / N_EDGES;
    int e = i - t * N_EDGES;
    int d = ei[(size_t)t * 2 * N_EDGES + N_EDGES + e];
    atomicAdd(&deg[t * N_NODES + d], 1);
}

// block scans 1024 items (256 thr x 4)
__global__ __launch_bounds__(256) void scan1_kernel(
    const int* __restrict__ deg, int* __restrict__ offs, int* __restrict__ bsum)
{
    __shared__ int s[256];
    int tid = threadIdx.x;
    int base = blockIdx.x * 1024 + tid * 4;
    int v[4];
    int tot = 0;
#pragma unroll
    for (int j = 0; j < 4; ++j) {
        v[j] = (base + j < NTOT) ? deg[base + j] : 0;
        tot += v[j];
    }
    s[tid] = tot;
    __syncthreads();
    for (int off = 1; off < 256; off <<= 1) {
        int t2 = (tid >= off) ? s[tid - off] : 0;
        __syncthreads();
        s[tid] += t2;
        __syncthreads();
    }
    if (tid == 255) bsum[blockIdx.x] = s[255];
    int run = s[tid] - tot;   // exclusive prefix of this thread
#pragma unroll
    for (int j = 0; j < 4; ++j) {
        if (base + j < NTOT) offs[base + j] = run;
        run += v[j];
    }
}

// single block scans the 684 block sums (exclusive, in place)
__global__ __launch_bounds__(1024) void scan2_kernel(int* __restrict__ bsum, int nb)
{
    __shared__ int s[1024];
    int tid = threadIdx.x;
    int v = (tid < nb) ? bsum[tid] : 0;
    s[tid] = v;
    __syncthreads();
    for (int off = 1; off < 1024; off <<= 1) {
        int t2 = (tid >= off) ? s[tid - off] : 0;
        __syncthreads();
        s[tid] += t2;
        __syncthreads();
    }
    if (tid < nb) bsum[tid] = s[tid] - v;   // exclusive
}

__global__ __launch_bounds__(256) void scan3_kernel(
    int* __restrict__ offs, const int* __restrict__ bsum)
{
    int i = blockIdx.x * 256 + threadIdx.x;
    if (i < NTOT) offs[i] += bsum[i >> 10];
    if (i == 0) offs[NTOT] = ETOT;
}

__global__ __launch_bounds__(256) void fill_kernel(
    const int* __restrict__ ei, int* __restrict__ cursor, int* __restrict__ srcperm)
{
    int i = blockIdx.x * 256 + threadIdx.x;
    if (i >= ETOT) return;
    int t = i / N_EDGES;
    int e = i - t * N_EDGES;
    const int* base = ei + (size_t)t * 2 * N_EDGES;
    int s = base[e];
    int d = base[N_EDGES + e];
    int pos = atomicAdd(&cursor[t * N_NODES + d], 1);
    srcperm[pos] = s;
}

// ---------------------------------------------------------------------------
// Aggregate: 32 lanes per node; sum x[src] rows over the node's CSR segment,
// divide by max(deg,1), write mean. No atomics.
// ---------------------------------------------------------------------------
__global__ __launch_bounds__(256) void aggregate_kernel(
    const float* __restrict__ x,
    const int* __restrict__ offs_t,     // offs + t*N_NODES
    const int* __restrict__ srcperm,
    float* __restrict__ mean)
{
    int g = blockIdx.x * 8 + (threadIdx.x >> 5);
    if (g >= N_NODES) return;
    int l = threadIdx.x & 31;
    int beg = offs_t[g];
    int end = offs_t[g + 1];
    float4 acc = make_float4(0.f, 0.f, 0.f, 0.f);
    for (int j = beg; j < end; ++j) {
        int s = srcperm[j];
        float4 v = *reinterpret_cast<const float4*>(x + (size_t)s * DIM + l * 4);
        acc.x += v.x; acc.y += v.y; acc.z += v.z; acc.w += v.w;
    }
    float inv = 1.0f / fmaxf((float)(end - beg), 1.0f);
    float4 o = make_float4(acc.x * inv, acc.y * inv, acc.z * inv, acc.w * inv);
    *reinterpret_cast<float4*>(mean + (size_t)g * DIM + l * 4) = o;
}

// ---------------------------------------------------------------------------
// out += (mean @ W + b) * (1/7)
// ---------------------------------------------------------------------------
#define BR 32
__global__ __launch_bounds__(256) void matmul_kernel(
    const float* __restrict__ mean,
    const float* __restrict__ W,      // [DIM][DIM], row k, col j
    const float* __restrict__ bias,   // [DIM]
    float* __restrict__ out)
{
    __shared__ float sW[32][DIM];     // 16 KB
    __shared__ float sM[BR][36];

    const int row0 = blockIdx.x * BR;
    const int cg = threadIdx.x & 31;
    const int rg = threadIdx.x >> 5;

    float acc[4][4];
#pragma unroll
    for (int r = 0; r < 4; ++r)
#pragma unroll
        for (int c = 0; c < 4; ++c) acc[r][c] = 0.f;

    for (int k0 = 0; k0 < DIM; k0 += 32) {
#pragma unroll
        for (int i = 0; i < 4; ++i) {
            int idx4 = threadIdx.x + i * 256;
            int kk = idx4 >> 5;
            int jc = idx4 & 31;
            *reinterpret_cast<float4*>(&sW[kk][jc * 4]) =
                *reinterpret_cast<const float4*>(&W[(size_t)(k0 + kk) * DIM + jc * 4]);
        }
        {
            int r = threadIdx.x >> 3;
            int kkc = threadIdx.x & 7;
            int row = row0 + r;
            float4 v = make_float4(0.f, 0.f, 0.f, 0.f);
            if (row < N_NODES)
                v = *reinterpret_cast<const float4*>(&mean[(size_t)row * DIM + k0 + kkc * 4]);
            *reinterpret_cast<float4*>(&sM[r][kkc * 4]) = v;
        }
        __syncthreads();

#pragma unroll
        for (int kk = 0; kk < 32; kk += 4) {
            float wv[4][4];
#pragma unroll
            for (int q = 0; q < 4; ++q) {
                float4 t = *reinterpret_cast<const float4*>(&sW[kk + q][cg * 4]);
                wv[q][0] = t.x; wv[q][1] = t.y; wv[q][2] = t.z; wv[q][3] = t.w;
            }
#pragma unroll
            for (int r = 0; r < 4; ++r) {
                float4 t = *reinterpret_cast<const float4*>(&sM[rg * 4 + r][kk]);
                float m[4] = {t.x, t.y, t.z, t.w};
#pragma unroll
                for (int q = 0; q < 4; ++q)
#pragma unroll
                    for (int c = 0; c < 4; ++c)
                        acc[r][c] += m[q] * wv[q][c];
            }
        }
        __syncthreads();
    }

    const float inv7 = 1.0f / 7.0f;
    float bj[4];
#pragma unroll
    for (int c = 0; c < 4; ++c) bj[c] = bias[cg * 4 + c];

#pragma unroll
    for (int r = 0; r < 4; ++r) {
        int row = row0 + rg * 4 + r;
        if (row < N_NODES) {
            float4* po = reinterpret_cast<float4*>(&out[(size_t)row * DIM + cg * 4]);
            float4 cur = *po;
            cur.x += (acc[r][0] + bj[0]) * inv7;
            cur.y += (acc[r][1] + bj[1]) * inv7;
            cur.z += (acc[r][2] + bj[2]) * inv7;
            cur.w += (acc[r][3] + bj[3]) * inv7;
            *po = cur;
        }
    }
}

extern "C" void kernel_launch(void* const* d_in, const int* in_sizes, int n_in,
                              void* d_out, int out_size, void* d_ws, size_t ws_size,
                              hipStream_t stream) {
    const float* x  = (const float*)d_in[0];
    const int*   ei = (const int*)d_in[1];     // [N_TYPES, 2, N_EDGES] int32
    const float* W  = (const float*)d_in[2];   // [N_TYPES, DIM, DIM]
    const float* b  = (const float*)d_in[3];   // [N_TYPES, DIM]
    float* out = (float*)d_out;

    // workspace layout
    float* meanbuf = (float*)d_ws;                         // N_NODES*DIM floats (51.2 MB)
    int* srcperm = (int*)(meanbuf + (size_t)N_NODES * DIM);// ETOT ints (11.2 MB)
    int* deg     = srcperm + ETOT;                         // NTOT
    int* offs    = deg + NTOT;                             // NTOT+1
    int* cursor  = offs + NTOT + 1;                        // NTOT
    int* bsum    = cursor + NTOT;                          // up to 1024

    const int NB = (NTOT + 1023) / 1024;                   // 684 scan blocks

    hipMemsetAsync(deg, 0, (size_t)NTOT * sizeof(int), stream);
    hist_kernel<<<(ETOT + 255) / 256, 256, 0, stream>>>(ei, deg);
    scan1_kernel<<<NB, 256, 0, stream>>>(deg, offs, bsum);
    scan2_kernel<<<1, 1024, 0, stream>>>(bsum, NB);
    scan3_kernel<<<(NTOT + 255) / 256, 256, 0, stream>>>(offs, bsum);
    hipMemcpyAsync(cursor, offs, (size_t)NTOT * sizeof(int),
                   hipMemcpyDeviceToDevice, stream);
    fill_kernel<<<(ETOT + 255) / 256, 256, 0, stream>>>(ei, cursor, srcperm);

    hipMemsetAsync(out, 0, (size_t)N_NODES * DIM * sizeof(float), stream);

    const int agg_blocks = (N_NODES + 7) / 8;              // 12500
    const int matmul_blocks = (N_NODES + BR - 1) / BR;     // 3125

    for (int t = 0; t < N_TYPES; ++t) {
        aggregate_kernel<<<agg_blocks, 256, 0, stream>>>(
            x, offs + (size_t)t * N_NODES, srcperm, meanbuf);
        matmul_kernel<<<matmul_blocks, 256, 0, stream>>>(
            meanbuf, W + (size_t)t * DIM * DIM, b + (size_t)t * DIM, out);
    }
}

// Round 3
// 527.923 us; speedup vs baseline: 10.0503x; 1.7770x over previous
//
#include <hip/hip_runtime.h>

#define N_NODES 100000
#define N_TYPES 7
#define N_EDGES 400000
#define DIM 128
#define NTOT (N_TYPES * N_NODES)   // 700000
#define ETOT (N_TYPES * N_EDGES)   // 2800000

typedef short v8s __attribute__((ext_vector_type(8)));   // 8 bf16 (4 VGPRs)
typedef float v4f __attribute__((ext_vector_type(4)));   // 4 f32 acc

__device__ __forceinline__ float bf2f(unsigned short u) {
    return __uint_as_float(((unsigned int)u) << 16);
}
__device__ __forceinline__ unsigned short f2bf(float f) {
    unsigned int x = __float_as_uint(f);
    return (unsigned short)((x + 0x7FFFu + ((x >> 16) & 1u)) >> 16);   // RNE
}

// ---------------------------------------------------------------------------
// casts
// ---------------------------------------------------------------------------
__global__ __launch_bounds__(256) void cast_x_kernel(
    const float* __restrict__ x, unsigned short* __restrict__ xb)
{
    int i = blockIdx.x * 256 + threadIdx.x;            // one float4 each
    if (i >= N_NODES * DIM / 4) return;
    float4 v = reinterpret_cast<const float4*>(x)[i];
    ushort4 o;
    o.x = f2bf(v.x); o.y = f2bf(v.y); o.z = f2bf(v.z); o.w = f2bf(v.w);
    reinterpret_cast<ushort4*>(xb)[i] = o;
}

// WT[t][j][k] = bf16(W[t][k][j])
__global__ __launch_bounds__(256) void cast_wt_kernel(
    const float* __restrict__ W, unsigned short* __restrict__ WT)
{
    int i = blockIdx.x * 256 + threadIdx.x;
    if (i >= N_TYPES * DIM * DIM) return;
    int t = i >> 14, r = i & 16383, j = r >> 7, k = r & 127;
    WT[i] = f2bf(W[(t << 14) + (k << 7) + j]);
}

__global__ __launch_bounds__(128) void bsum_kernel(
    const float* __restrict__ b, float* __restrict__ bsum)
{
    int j = threadIdx.x;
    float s = 0.f;
    for (int t = 0; t < N_TYPES; ++t) s += b[t * DIM + j];
    bsum[j] = s;
}

// ---------------------------------------------------------------------------
// CSR build. type = blockIdx&7 so each XCD's L2 owns one type's slices.
// ---------------------------------------------------------------------------
#define BPT 256
__global__ __launch_bounds__(256) void hist_kernel(
    const int* __restrict__ ei, int* __restrict__ deg)
{
    int m = blockIdx.x & 7;
    if (m >= N_TYPES) return;
    int bi = blockIdx.x >> 3;
    const int* dstp = ei + (size_t)m * 2 * N_EDGES + N_EDGES;
    int* degt = deg + m * N_NODES;
    for (int e = bi * 256 + threadIdx.x; e < N_EDGES; e += BPT * 256)
        atomicAdd(&degt[dstp[e]], 1);
}

__global__ __launch_bounds__(256) void scan1_kernel(
    const int* __restrict__ deg, int* __restrict__ offs, int* __restrict__ bsum)
{
    __shared__ int s[256];
    int tid = threadIdx.x;
    int base = blockIdx.x * 1024 + tid * 4;
    int v[4];
    int tot = 0;
#pragma unroll
    for (int j = 0; j < 4; ++j) {
        v[j] = (base + j < NTOT) ? deg[base + j] : 0;
        tot += v[j];
    }
    s[tid] = tot;
    __syncthreads();
    for (int off = 1; off < 256; off <<= 1) {
        int t2 = (tid >= off) ? s[tid - off] : 0;
        __syncthreads();
        s[tid] += t2;
        __syncthreads();
    }
    if (tid == 255) bsum[blockIdx.x] = s[255];
    int run = s[tid] - tot;
#pragma unroll
    for (int j = 0; j < 4; ++j) {
        if (base + j < NTOT) offs[base + j] = run;
        run += v[j];
    }
}

__global__ __launch_bounds__(1024) void scan2_kernel(int* __restrict__ bsum, int nb)
{
    __shared__ int s[1024];
    int tid = threadIdx.x;
    int v = (tid < nb) ? bsum[tid] : 0;
    s[tid] = v;
    __syncthreads();
    for (int off = 1; off < 1024; off <<= 1) {
        int t2 = (tid >= off) ? s[tid - off] : 0;
        __syncthreads();
        s[tid] += t2;
        __syncthreads();
    }
    if (tid < nb) bsum[tid] = s[tid] - v;
}

__global__ __launch_bounds__(256) void scan3_kernel(
    int* __restrict__ offs, int* __restrict__ cursor, const int* __restrict__ bsum)
{
    int i = blockIdx.x * 256 + threadIdx.x;
    if (i < NTOT) {
        int v = offs[i] + bsum[i >> 10];
        offs[i] = v;
        cursor[i] = v;
    }
    if (i == 0) offs[NTOT] = ETOT;
}

__global__ __launch_bounds__(256) void fill_kernel(
    const int* __restrict__ ei, int* __restrict__ cursor, int* __restrict__ srcperm)
{
    int m = blockIdx.x & 7;
    if (m >= N_TYPES) return;
    int bi = blockIdx.x >> 3;
    const int* base = ei + (size_t)m * 2 * N_EDGES;
    int* curt = cursor + m * N_NODES;
    for (int e = bi * 256 + threadIdx.x; e < N_EDGES; e += BPT * 256) {
        int s = base[e];
        int d = base[N_EDGES + e];
        int pos = atomicAdd(&curt[d], 1);
        srcperm[pos] = s;
    }
}

// ---------------------------------------------------------------------------
// Aggregate (bf16 gather, f32 accum, bf16 mean out). 32 lanes per node.
// ---------------------------------------------------------------------------
#define AGG_BPT ((N_NODES + 7) / 8)   // 12500 blocks per type
__global__ __launch_bounds__(256) void aggregate_kernel(
    const unsigned short* __restrict__ xb,
    const int* __restrict__ offs,
    const int* __restrict__ srcperm,
    unsigned short* __restrict__ meanout,
    int t0, size_t meanStride)
{
    int bt = blockIdx.x / AGG_BPT;
    int bb = blockIdx.x - bt * AGG_BPT;
    int t = t0 + bt;
    int g = bb * 8 + (threadIdx.x >> 5);
    if (g >= N_NODES) return;
    int l = threadIdx.x & 31;
    const int* offt = offs + (size_t)t * N_NODES;
    int beg = offt[g], end = offt[g + 1];
    float a0 = 0.f, a1 = 0.f, a2 = 0.f, a3 = 0.f;
    for (int e = beg; e < end; ++e) {
        int s = srcperm[e];
        ushort4 v = *reinterpret_cast<const ushort4*>(xb + ((size_t)s << 7) + (l << 2));
        a0 += bf2f(v.x); a1 += bf2f(v.y); a2 += bf2f(v.z); a3 += bf2f(v.w);
    }
    float inv = 1.0f / fmaxf((float)(end - beg), 1.0f);
    ushort4 o;
    o.x = f2bf(a0 * inv); o.y = f2bf(a1 * inv); o.z = f2bf(a2 * inv); o.w = f2bf(a3 * inv);
    *reinterpret_cast<ushort4*>(meanout + (size_t)bt * meanStride + ((size_t)g << 7) + (l << 2)) = o;
}

// ---------------------------------------------------------------------------
// MFMA GEMM: out[100k][128] (f32) = sum_t mean_t[100k][128] @ W_t + bsum, /7.
// Block: 256 thr = 4 waves, 64 rows x 128 cols. B (=W^T) staged in LDS,
// XOR-swizzled for conflict-free ds_read_b128.
// ---------------------------------------------------------------------------
__global__ __launch_bounds__(256) void matmul_kernel(
    const unsigned short* __restrict__ meanall, size_t meanStride,
    int t0, int nt,
    const unsigned short* __restrict__ WT,
    const float* __restrict__ bsum,
    float* __restrict__ out, int accum)
{
    __shared__ unsigned short sB[DIM * DIM];   // 32 KB, swizzled

    const int tid = threadIdx.x;
    const int wave = tid >> 6;
    const int lane = tid & 63;
    const int rlo = lane & 15;
    const int khi = lane >> 4;                 // 0..3
    const int row0 = blockIdx.x * 64 + wave * 16;

    v4f acc[8];
#pragma unroll
    for (int n = 0; n < 8; ++n) acc[n] = (v4f){0.f, 0.f, 0.f, 0.f};

    for (int tt = 0; tt < nt; ++tt) {
        int t = t0 + tt;
        __syncthreads();
        // stage WT_t: 2048 x 16B chunks, 8 per thread, XOR-swizzled dest
        const uint4* gw = reinterpret_cast<const uint4*>(WT + ((size_t)t << 14));
#pragma unroll
        for (int i = 0; i < 8; ++i) {
            int c = tid + (i << 8);            // 0..2047
            uint4 v = gw[c];
            int L = c << 4;
            int row = L >> 8;
            int sb = (row << 8) | ((L & 255) ^ ((row & 7) << 4));
            *reinterpret_cast<uint4*>(reinterpret_cast<char*>(sB) + sb) = v;
        }
        __syncthreads();

        int rowA = row0 + rlo;
        if (rowA >= N_NODES) rowA = N_NODES - 1;
        const unsigned short* arow = meanall + (size_t)tt * meanStride + ((size_t)rowA << 7);

#pragma unroll
        for (int k0 = 0; k0 < DIM; k0 += 32) {
            v8s a = *reinterpret_cast<const v8s*>(arow + k0 + (khi << 3));
#pragma unroll
            for (int n = 0; n < 8; ++n) {
                int jrow = (n << 4) | rlo;
                int kb = (k0 + (khi << 3)) << 1;
                int sb = (jrow << 8) | (kb ^ ((jrow & 7) << 4));
                v8s bf = *reinterpret_cast<const v8s*>(reinterpret_cast<char*>(sB) + sb);
                acc[n] = __builtin_amdgcn_mfma_f32_16x16x32_bf16(a, bf, acc[n], 0, 0, 0);
            }
        }
    }

    const float inv7 = 1.0f / 7.0f;
#pragma unroll
    for (int n = 0; n < 8; ++n) {
        int col = (n << 4) | rlo;
        float bs = bsum[col];
#pragma unroll
        for (int r = 0; r < 4; ++r) {
            int row = row0 + (khi << 2) + r;
            if (row < N_NODES) {
                float* p = out + ((size_t)row << 7) + col;
                if (accum) *p += acc[n][r] * inv7;
                else       *p = (acc[n][r] + bs) * inv7;
            }
        }
    }
}

__global__ __launch_bounds__(256) void out_init_kernel(
    const float* __restrict__ bsum, float* __restrict__ out)
{
    int i = blockIdx.x * 256 + threadIdx.x;    // one float4 each
    if (i >= N_NODES * DIM / 4) return;
    int c4 = (i & 31) * 4;
    const float inv7 = 1.0f / 7.0f;
    float4 bv = *reinterpret_cast<const float4*>(bsum + c4);
    float4 o = make_float4(bv.x * inv7, bv.y * inv7, bv.z * inv7, bv.w * inv7);
    reinterpret_cast<float4*>(out)[i] = o;
}

extern "C" void kernel_launch(void* const* d_in, const int* in_sizes, int n_in,
                              void* d_out, int out_size, void* d_ws, size_t ws_size,
                              hipStream_t stream) {
    const float* x  = (const float*)d_in[0];
    const int*   ei = (const int*)d_in[1];     // [N_TYPES, 2, N_EDGES] int32
    const float* W  = (const float*)d_in[2];
    const float* b  = (const float*)d_in[3];
    float* out = (float*)d_out;

    // ---- workspace layout (bytes) ----
    char* p = (char*)d_ws;
    unsigned short* xb = (unsigned short*)p;          p += (size_t)N_NODES * DIM * 2;       // 25.6 MB
    unsigned short* WT = (unsigned short*)p;          p += (size_t)N_TYPES * DIM * DIM * 2; // 229 KB
    float* bsum = (float*)p;                          p += 512;
    int* srcperm = (int*)p;                           p += (size_t)ETOT * 4;                // 11.2 MB
    int* deg = (int*)p;                               p += (size_t)NTOT * 4;
    int* offs = (int*)p;                              p += (size_t)(NTOT + 1) * 4;
    int* cursor = (int*)p;                            p += (size_t)NTOT * 4;
    int* bscan = (int*)p;                             p += 1024 * 4;
    // align mean buffer to 16B
    p = (char*)(((uintptr_t)p + 15) & ~(uintptr_t)15);
    unsigned short* meanbuf = (unsigned short*)p;
    size_t mean1_bytes = (size_t)N_NODES * DIM * 2;   // 25.6 MB per type
    size_t used = (size_t)(p - (char*)d_ws);
    bool fused = (ws_size >= used + 7 * mean1_bytes);

    const int NB = (NTOT + 1023) / 1024;              // 684

    cast_x_kernel<<<(N_NODES * DIM / 4 + 255) / 256, 256, 0, stream>>>(x, xb);
    cast_wt_kernel<<<(N_TYPES * DIM * DIM + 255) / 256, 256, 0, stream>>>(W, WT);
    bsum_kernel<<<1, 128, 0, stream>>>(b, bsum);

    hipMemsetAsync(deg, 0, (size_t)NTOT * sizeof(int), stream);
    hist_kernel<<<BPT * 8, 256, 0, stream>>>(ei, deg);
    scan1_kernel<<<NB, 256, 0, stream>>>(deg, offs, bscan);
    scan2_kernel<<<1, 1024, 0, stream>>>(bscan, NB);
    scan3_kernel<<<(NTOT + 255) / 256, 256, 0, stream>>>(offs, cursor, bscan);
    fill_kernel<<<BPT * 8, 256, 0, stream>>>(ei, cursor, srcperm);

    const int matmul_blocks = (N_NODES + 63) / 64;    // 1563

    if (fused) {
        size_t meanStride = (size_t)N_NODES * DIM;    // in ushorts
        aggregate_kernel<<<7 * AGG_BPT, 256, 0, stream>>>(
            xb, offs, srcperm, meanbuf, 0, meanStride);
        matmul_kernel<<<matmul_blocks, 256, 0, stream>>>(
            meanbuf, meanStride, 0, N_TYPES, WT, bsum, out, 0);
    } else {
        out_init_kernel<<<(N_NODES * DIM / 4 + 255) / 256, 256, 0, stream>>>(bsum, out);
        for (int t = 0; t < N_TYPES; ++t) {
            aggregate_kernel<<<AGG_BPT, 256, 0, stream>>>(
                xb, offs, srcperm, meanbuf, t, 0);
            matmul_kernel<<<matmul_blocks, 256, 0, stream>>>(
                meanbuf, 0, t, 1, WT, bsum, out, 1);
        }
    }
}